// Round 9
// baseline (471.319 us; speedup 1.0000x reference)
//
#include <hip/hip_runtime.h>
#include <hip/hip_fp16.h>

// Problem constants (match reference)
#define NRAYS 1048576
#define NV 32
#define ND 32
#define NF 6
#define NK 13  // 2F+1

typedef _Float16 h2 __attribute__((ext_vector_type(2)));
typedef float f4 __attribute__((ext_vector_type(4)));

__device__ __forceinline__ float fdot2acc(h2 a, h2 b, float c) {
#if __has_builtin(__builtin_amdgcn_fdot2)
    return __builtin_amdgcn_fdot2(a, b, c, false);
#else
    return c + (float)a.x * (float)b.x + (float)a.y * (float)b.y;
#endif
}

__device__ __forceinline__ h2 pack2(float a, float b) {
#if __has_builtin(__builtin_amdgcn_cvt_pkrtz)
    return __builtin_bit_cast(h2, __builtin_amdgcn_cvt_pkrtz(a, b));
#else
    h2 r; r.x = (_Float16)a; r.y = (_Float16)b; return r;
#endif
}

__device__ __forceinline__ float hwsin(float rev) {
#if __has_builtin(__builtin_amdgcn_sinf)
    return __builtin_amdgcn_sinf(rev);
#else
    return __sinf(6.28318530717958647692f * rev);
#endif
}
__device__ __forceinline__ float hwcos(float rev) {
#if __has_builtin(__builtin_amdgcn_cosf)
    return __builtin_amdgcn_cosf(rev);
#else
    return __cosf(6.28318530717958647692f * rev);
#endif
}

__device__ __forceinline__ void make_basis(float t, h2 bp[7]) {
    float sv[NF], cv[NF];
    sv[0] = hwsin(0.5f * t);
    cv[0] = hwcos(0.5f * t);
#pragma unroll
    for (int j = 1; j < NF; ++j) {
        float sj = sv[j - 1], cj = cv[j - 1];
        sv[j] = 2.f * sj * cj;
        cv[j] = fmaf(-2.f * sj, sj, 1.f);
    }
    bp[0] = pack2(1.0f, sv[0]);
    bp[1] = pack2(sv[1], sv[2]);
    bp[2] = pack2(sv[3], sv[4]);
    bp[3] = pack2(sv[5], cv[0]);
    bp[4] = pack2(cv[1], cv[2]);
    bp[5] = pack2(cv[3], cv[4]);
    bp[6] = pack2(cv[5], 0.0f);  // pad half must be 0
}

// ---------------------------------------------------------------------------
// Kernel A: pack f32 weights into the v&7-XOR-swizzled f16 image (see R5).
__global__ void pack_weights_kernel(const float* __restrict__ weights,
                                    unsigned* __restrict__ wpack)
{
    int j = blockIdx.x * 256 + threadIdx.x;  // 0 .. 7167 (dwords)
    if (j >= NV * 7 * 32) return;
    int v = j / 224;
    int r = j - v * 224;
    int i = r >> 5;
    int c = r & 31;
    int pos = c >> 2;
    int e = c & 3;
    int q = pos ^ (v & 7);
    int d = 4 * q + e;
    float w0 = weights[v * (ND * NK) + d * NK + 2 * i];
    float w1 = (2 * i + 1 < NK) ? weights[v * (ND * NK) + d * NK + 2 * i + 1] : 0.f;
    wpack[j] = __builtin_bit_cast(unsigned, pack2(w0, w1));
}

// ---------------------------------------------------------------------------
// Production kernel: R7 verbatim (best known: 36.18 us).
__global__ __launch_bounds__(256, 5) void VideoEmbedding_kernel(
    const float* __restrict__ times,
    const int* __restrict__ vids,
    const unsigned* __restrict__ wpack,
    float* __restrict__ out)
{
    __shared__ _Float16 wl[NV * 7 * ND * 2];

    const int tid = threadIdx.x;
    {
        const uint4* src = reinterpret_cast<const uint4*>(wpack);
        uint4* dst = reinterpret_cast<uint4*>(wl);
#pragma unroll
        for (int j = 0; j < 7; ++j)
            dst[tid + j * 256] = src[tid + j * 256];
    }
    __syncthreads();

    const int q = tid & 7;
    const int gstride = (gridDim.x * 256) >> 3;
    int ray = ((blockIdx.x * 256) + tid) >> 3;

    float tt0 = times[ray];
    int vv0 = vids[ray];
    int r1 = min(ray + gstride, NRAYS - 1);
    float tt1 = times[r1];
    int vv1 = vids[r1];

    while (ray < NRAYS) {
        const int rayB = ray + gstride;
        const int rn0 = min(ray + 2 * gstride, NRAYS - 1);
        const int rn1 = min(ray + 3 * gstride, NRAYS - 1);
        const float tn0 = times[rn0], tn1 = times[rn1];
        const int vn0 = vids[rn0], vn1 = vids[rn1];

        const float tt[2] = {tt0, tt1};
        const int vv[2] = {vv0, vv1};
        f4 res[2];
#pragma unroll
        for (int u = 0; u < 2; ++u) {
            h2 bp[7];
            make_basis(tt[u], bp);
            const unsigned pos = (unsigned)(q ^ (vv[u] & 7));
            const unsigned base = (unsigned)vv[u] * 448u + pos * 8u;
            float a0 = 0.f, a1 = 0.f, a2 = 0.f, a3 = 0.f;
#pragma unroll
            for (int i = 0; i < 7; ++i) {
                uint4 w = *reinterpret_cast<const uint4*>(&wl[base + i * 64]);
                a0 = fdot2acc(__builtin_bit_cast(h2, w.x), bp[i], a0);
                a1 = fdot2acc(__builtin_bit_cast(h2, w.y), bp[i], a1);
                a2 = fdot2acc(__builtin_bit_cast(h2, w.z), bp[i], a2);
                a3 = fdot2acc(__builtin_bit_cast(h2, w.w), bp[i], a3);
            }
            res[u].x = a0; res[u].y = a1; res[u].z = a2; res[u].w = a3;
        }

        __builtin_nontemporal_store(res[0],
            reinterpret_cast<f4*>(out) + (size_t)ray * 8 + q);
        if (rayB < NRAYS)
            __builtin_nontemporal_store(res[1],
                reinterpret_cast<f4*>(out) + (size_t)rayB * 8 + q);

        ray += 2 * gstride;
        tt0 = tn0; vv0 = vn0;
        tt1 = tn1; vv1 = vn1;
    }
}

// ---------------------------------------------------------------------------
// Diagnostic shadows (write d_ws only; sized to displace the ~80us poison
// fills from the top-5 counter table).
// MODE 0 = full pipeline (production proxy), reps=4  (~145 us)
// MODE 1 = LDS reads ablated (hash weights), reps=8  -> /8 = non-LDS time
// MODE 2 = stores ablated (result-dependent never-true guard), reps=12
template<int MODE>
__global__ __launch_bounds__(256, 5) void shadow_kernel(
    const float* __restrict__ times,
    const int* __restrict__ vids,
    const unsigned* __restrict__ wpack,
    f4* __restrict__ wsout,
    int reps)
{
    __shared__ _Float16 wl[NV * 7 * ND * 2];

    const int tid = threadIdx.x;
    {   // stage in ALL modes so occupancy/preamble are identical
        const uint4* src = reinterpret_cast<const uint4*>(wpack);
        uint4* dst = reinterpret_cast<uint4*>(wl);
#pragma unroll
        for (int j = 0; j < 7; ++j)
            dst[tid + j * 256] = src[tid + j * 256];
    }
    __syncthreads();

    const int q = tid & 7;
    const int gstride = (gridDim.x * 256) >> 3;
    const int slot0 = ((blockIdx.x * 256) + tid) >> 3;

    for (int rep = 0; rep < reps; ++rep) {
        int ray = slot0;
        float t = times[ray];
        int vid = vids[ray];
        while (ray < NRAYS) {
            const int nray = ray + gstride;
            const int rn = nray < NRAYS ? nray : 0;
            const float tn = times[rn];
            const int vn = vids[rn];

            h2 bp[7];
            make_basis(t, bp);

            float a0 = 0.f, a1 = 0.f, a2 = 0.f, a3 = 0.f;
            if constexpr (MODE == 1) {
                // synthesized weights: vid/q stay live, no ds_read
                unsigned h = ((unsigned)vid * 2654435761u) ^ ((unsigned)q * 97u);
                uint4 w;
                w.x = h; w.y = h ^ 0x55555555u; w.z = h * 3u; w.w = h ^ 0xAAAA5555u;
#pragma unroll
                for (int i = 0; i < 7; ++i) {
                    a0 = fdot2acc(__builtin_bit_cast(h2, w.x), bp[i], a0);
                    a1 = fdot2acc(__builtin_bit_cast(h2, w.y), bp[i], a1);
                    a2 = fdot2acc(__builtin_bit_cast(h2, w.z), bp[i], a2);
                    a3 = fdot2acc(__builtin_bit_cast(h2, w.w), bp[i], a3);
                }
            } else {
                const unsigned pos = (unsigned)(q ^ (vid & 7));
                const unsigned base = (unsigned)vid * 448u + pos * 8u;
#pragma unroll
                for (int i = 0; i < 7; ++i) {
                    uint4 w = *reinterpret_cast<const uint4*>(&wl[base + i * 64]);
                    a0 = fdot2acc(__builtin_bit_cast(h2, w.x), bp[i], a0);
                    a1 = fdot2acc(__builtin_bit_cast(h2, w.y), bp[i], a1);
                    a2 = fdot2acc(__builtin_bit_cast(h2, w.z), bp[i], a2);
                    a3 = fdot2acc(__builtin_bit_cast(h2, w.w), bp[i], a3);
                }
            }

            f4 res;
            res.x = a0; res.y = a1; res.z = a2; res.w = a3;
            if constexpr (MODE == 2) {
                // guard depends on RESULT (finite) vs a NaN bit pattern:
                // never true, but compute cannot be sunk into the branch.
                if (__builtin_bit_cast(unsigned, res.x) == 0x7F123456u)
                    wsout[(size_t)ray * 8 + q] = res;
            } else {
                __builtin_nontemporal_store(res, wsout + (size_t)ray * 8 + q);
            }

            ray = nray;
            t = tn;
            vid = vn;
        }
    }
}

extern "C" void kernel_launch(void* const* d_in, const int* in_sizes, int n_in,
                              void* d_out, int out_size, void* d_ws, size_t ws_size,
                              hipStream_t stream) {
    const float* times = (const float*)d_in[0];
    const int* vids = (const int*)d_in[1];
    const float* weights = (const float*)d_in[2];
    float* out = (float*)d_out;
    unsigned* wpack = (unsigned*)d_ws;
    // shadow output: 16 MiB into ws (ws is >=512 MiB per harness poison fills)
    f4* wsout = (f4*)((char*)d_ws + (size_t)(16u << 20));

    hipLaunchKernelGGL(pack_weights_kernel, dim3(28), dim3(256), 0, stream,
                       weights, wpack);
    hipLaunchKernelGGL(VideoEmbedding_kernel, dim3(1280), dim3(256), 0, stream,
                       times, vids, wpack, out);
    hipLaunchKernelGGL((shadow_kernel<0>), dim3(1280), dim3(256), 0, stream,
                       times, vids, wpack, wsout, 4);
    hipLaunchKernelGGL((shadow_kernel<1>), dim3(1280), dim3(256), 0, stream,
                       times, vids, wpack, wsout, 8);
    hipLaunchKernelGGL((shadow_kernel<2>), dim3(1280), dim3(256), 0, stream,
                       times, vids, wpack, wsout, 12);
}

// Round 10
// 34.976 us; speedup vs baseline: 13.4753x; 13.4753x over previous
//
#include <hip/hip_runtime.h>
#include <hip/hip_fp16.h>

// Problem constants (match reference)
#define NRAYS 1048576
#define NV 32
#define ND 32
#define NF 6
#define NK 13  // 2F+1

typedef _Float16 h2 __attribute__((ext_vector_type(2)));
typedef float f4 __attribute__((ext_vector_type(4)));

__device__ __forceinline__ float fdot2acc(h2 a, h2 b, float c) {
#if __has_builtin(__builtin_amdgcn_fdot2)
    return __builtin_amdgcn_fdot2(a, b, c, false);
#else
    return c + (float)a.x * (float)b.x + (float)a.y * (float)b.y;
#endif
}

__device__ __forceinline__ h2 pack2(float a, float b) {
#if __has_builtin(__builtin_amdgcn_cvt_pkrtz)
    return __builtin_bit_cast(h2, __builtin_amdgcn_cvt_pkrtz(a, b));
#else
    h2 r; r.x = (_Float16)a; r.y = (_Float16)b; return r;
#endif
}

__device__ __forceinline__ float hwsin(float rev) {
#if __has_builtin(__builtin_amdgcn_sinf)
    return __builtin_amdgcn_sinf(rev);
#else
    return __sinf(6.28318530717958647692f * rev);
#endif
}
__device__ __forceinline__ float hwcos(float rev) {
#if __has_builtin(__builtin_amdgcn_cosf)
    return __builtin_amdgcn_cosf(rev);
#else
    return __cosf(6.28318530717958647692f * rev);
#endif
}

__device__ __forceinline__ void make_basis(float t, h2 bp[7]) {
    float sv[NF], cv[NF];
    sv[0] = hwsin(0.5f * t);
    cv[0] = hwcos(0.5f * t);
#pragma unroll
    for (int j = 1; j < NF; ++j) {
        float sj = sv[j - 1], cj = cv[j - 1];
        sv[j] = 2.f * sj * cj;
        cv[j] = fmaf(-2.f * sj, sj, 1.f);
    }
    bp[0] = pack2(1.0f, sv[0]);
    bp[1] = pack2(sv[1], sv[2]);
    bp[2] = pack2(sv[3], sv[4]);
    bp[3] = pack2(sv[5], cv[0]);
    bp[4] = pack2(cv[1], cv[2]);
    bp[5] = pack2(cv[3], cv[4]);
    bp[6] = pack2(cv[5], 0.0f);  // pad half must be 0
}

// ---------------------------------------------------------------------------
// Kernel A: pack f32 weights into the v&7-XOR-swizzled f16 image (see R5).
__global__ void pack_weights_kernel(const float* __restrict__ weights,
                                    unsigned* __restrict__ wpack)
{
    int j = blockIdx.x * 256 + threadIdx.x;  // 0 .. 7167 (dwords)
    if (j >= NV * 7 * 32) return;
    int v = j / 224;
    int r = j - v * 224;
    int i = r >> 5;
    int c = r & 31;
    int pos = c >> 2;
    int e = c & 3;
    int q = pos ^ (v & 7);
    int d = 4 * q + e;
    float w0 = weights[v * (ND * NK) + d * NK + 2 * i];
    float w1 = (2 * i + 1 < NK) ? weights[v * (ND * NK) + d * NK + 2 * i + 1] : 0.f;
    wpack[j] = __builtin_bit_cast(unsigned, pack2(w0, w1));
}

// ---------------------------------------------------------------------------
// Main kernel. 8 threads per ray: thread q owns d = 4q..4q+3.
// Register double-buffered LDS pipeline: ds_reads for ray i+1 issue into the
// alternate buffer while ray i computes from the buffer filled last iter.
// Plain (cached) stores: MODE1 shadow showed nt stores cap at 5.1 TB/s vs
// 6.6-6.9 TB/s for plain-store fill kernels.
__global__ __launch_bounds__(256, 5) void VideoEmbedding_kernel(
    const float* __restrict__ times,
    const int* __restrict__ vids,
    const unsigned* __restrict__ wpack,
    float* __restrict__ out)
{
    __shared__ _Float16 wl[NV * 7 * ND * 2];  // 28672 B -> 5 blocks/CU

    const int tid = threadIdx.x;
    {
        const uint4* src = reinterpret_cast<const uint4*>(wpack);
        uint4* dst = reinterpret_cast<uint4*>(wl);
#pragma unroll
        for (int j = 0; j < 7; ++j)
            dst[tid + j * 256] = src[tid + j * 256];
    }
    __syncthreads();

    const int q = tid & 7;
    const int gs = (gridDim.x * 256) >> 3;  // 40960 ray-slots
    int ray = ((blockIdx.x * 256) + tid) >> 3;

    // t/vid ring: current, +1, +2 (global prefetch depth 2)
    float t0, t1, t2;
    int v0, v1, v2;
    t0 = times[ray]; v0 = vids[ray];
    int rr = min(ray + gs, NRAYS - 1);
    t1 = times[rr]; v1 = vids[rr];
    rr = min(ray + 2 * gs, NRAYS - 1);
    t2 = times[rr]; v2 = vids[rr];

    uint4 wA[7], wB[7];

    // preload weights for the first ray into wA
    {
        const unsigned base = (unsigned)v0 * 448u + (unsigned)(q ^ (v0 & 7)) * 8u;
#pragma unroll
        for (int i = 0; i < 7; ++i)
            wA[i] = *reinterpret_cast<const uint4*>(&wl[base + i * 64]);
    }

#define STAGE(WCUR, WNEXT)                                                    \
    {                                                                         \
        /* global prefetch for ray+3 */                                       \
        rr = min(ray + 3 * gs, NRAYS - 1);                                    \
        const float t3 = times[rr];                                           \
        const int v3 = vids[rr];                                              \
        /* issue LDS reads for ray+1 into WNEXT */                            \
        {                                                                     \
            const unsigned nb =                                               \
                (unsigned)v1 * 448u + (unsigned)(q ^ (v1 & 7)) * 8u;          \
            _Pragma("unroll")                                                 \
            for (int i = 0; i < 7; ++i)                                       \
                WNEXT[i] = *reinterpret_cast<const uint4*>(&wl[nb + i * 64]); \
        }                                                                     \
        /* compute + store current ray from WCUR */                           \
        {                                                                     \
            h2 bp[7];                                                         \
            make_basis(t0, bp);                                               \
            float a0 = 0.f, a1 = 0.f, a2 = 0.f, a3 = 0.f;                     \
            _Pragma("unroll")                                                 \
            for (int i = 0; i < 7; ++i) {                                     \
                a0 = fdot2acc(__builtin_bit_cast(h2, WCUR[i].x), bp[i], a0);  \
                a1 = fdot2acc(__builtin_bit_cast(h2, WCUR[i].y), bp[i], a1);  \
                a2 = fdot2acc(__builtin_bit_cast(h2, WCUR[i].z), bp[i], a2);  \
                a3 = fdot2acc(__builtin_bit_cast(h2, WCUR[i].w), bp[i], a3);  \
            }                                                                 \
            f4 res;                                                           \
            res.x = a0; res.y = a1; res.z = a2; res.w = a3;                   \
            reinterpret_cast<f4*>(out)[(size_t)ray * 8 + q] = res;            \
        }                                                                     \
        ray += gs;                                                            \
        if (ray >= NRAYS) break;                                              \
        t0 = t1; t1 = t2; t2 = t3;                                            \
        v0 = v1; v1 = v2; v2 = v3;                                            \
    }

    while (true) {
        STAGE(wA, wB)   // even iteration: compute from wA, fill wB
        STAGE(wB, wA)   // odd iteration: compute from wB, fill wA
    }
#undef STAGE
}

extern "C" void kernel_launch(void* const* d_in, const int* in_sizes, int n_in,
                              void* d_out, int out_size, void* d_ws, size_t ws_size,
                              hipStream_t stream) {
    const float* times = (const float*)d_in[0];
    const int* vids = (const int*)d_in[1];
    const float* weights = (const float*)d_in[2];
    float* out = (float*)d_out;
    unsigned* wpack = (unsigned*)d_ws;

    hipLaunchKernelGGL(pack_weights_kernel, dim3(28), dim3(256), 0, stream,
                       weights, wpack);
    // 1280 blocks = 5 blocks/CU (LDS-limited at 28672 B/block), grid-stride.
    hipLaunchKernelGGL(VideoEmbedding_kernel, dim3(1280), dim3(256), 0, stream,
                       times, vids, wpack, out);
}

// Round 11
// 33.771 us; speedup vs baseline: 13.9563x; 1.0357x over previous
//
#include <hip/hip_runtime.h>
#include <hip/hip_fp16.h>

// Problem constants (match reference)
#define NRAYS 1048576
#define NV 32
#define ND 32
#define NF 6
#define NK 13  // 2F+1

typedef _Float16 h2 __attribute__((ext_vector_type(2)));
typedef float f4 __attribute__((ext_vector_type(4)));

__device__ __forceinline__ float fdot2acc(h2 a, h2 b, float c) {
#if __has_builtin(__builtin_amdgcn_fdot2)
    return __builtin_amdgcn_fdot2(a, b, c, false);
#else
    return c + (float)a.x * (float)b.x + (float)a.y * (float)b.y;
#endif
}

__device__ __forceinline__ h2 pack2(float a, float b) {
#if __has_builtin(__builtin_amdgcn_cvt_pkrtz)
    return __builtin_bit_cast(h2, __builtin_amdgcn_cvt_pkrtz(a, b));
#else
    h2 r; r.x = (_Float16)a; r.y = (_Float16)b; return r;
#endif
}

__device__ __forceinline__ float hwsin(float rev) {
#if __has_builtin(__builtin_amdgcn_sinf)
    return __builtin_amdgcn_sinf(rev);
#else
    return __sinf(6.28318530717958647692f * rev);
#endif
}
__device__ __forceinline__ float hwcos(float rev) {
#if __has_builtin(__builtin_amdgcn_cosf)
    return __builtin_amdgcn_cosf(rev);
#else
    return __cosf(6.28318530717958647692f * rev);
#endif
}

__device__ __forceinline__ void make_basis(float t, h2 bp[7]) {
    float sv[NF], cv[NF];
    sv[0] = hwsin(0.5f * t);
    cv[0] = hwcos(0.5f * t);
#pragma unroll
    for (int j = 1; j < NF; ++j) {
        float sj = sv[j - 1], cj = cv[j - 1];
        sv[j] = 2.f * sj * cj;
        cv[j] = fmaf(-2.f * sj, sj, 1.f);
    }
    bp[0] = pack2(1.0f, sv[0]);
    bp[1] = pack2(sv[1], sv[2]);
    bp[2] = pack2(sv[3], sv[4]);
    bp[3] = pack2(sv[5], cv[0]);
    bp[4] = pack2(cv[1], cv[2]);
    bp[5] = pack2(cv[3], cv[4]);
    bp[6] = pack2(cv[5], 0.0f);  // pad half must be 0
}

// ---------------------------------------------------------------------------
// Kernel A: pack f32 weights into the v&7-XOR-swizzled f16 image (see R5).
__global__ void pack_weights_kernel(const float* __restrict__ weights,
                                    unsigned* __restrict__ wpack)
{
    int j = blockIdx.x * 256 + threadIdx.x;  // 0 .. 7167 (dwords)
    if (j >= NV * 7 * 32) return;
    int v = j / 224;
    int r = j - v * 224;
    int i = r >> 5;
    int c = r & 31;
    int pos = c >> 2;
    int e = c & 3;
    int q = pos ^ (v & 7);
    int d = 4 * q + e;
    float w0 = weights[v * (ND * NK) + d * NK + 2 * i];
    float w1 = (2 * i + 1 < NK) ? weights[v * (ND * NK) + d * NK + 2 * i + 1] : 0.f;
    wpack[j] = __builtin_bit_cast(unsigned, pack2(w0, w1));
}

// ---------------------------------------------------------------------------
// Main kernel. Block owns 512 contiguous rays. ALL global loads issue in the
// prologue (before any store) -> inner loop's vmcnt queue holds only stores,
// which nothing waits on: kills the load/store vmcnt convoy (R9 diagnosis).
// 8 threads per ray: thread q owns d = 4q..4q+3. Weight regs double-buffered.
__global__ __launch_bounds__(256, 5) void VideoEmbedding_kernel(
    const float* __restrict__ times,
    const int* __restrict__ vids,
    const unsigned* __restrict__ wpack,
    float* __restrict__ out)
{
    __shared__ _Float16 wl[NV * 7 * ND * 2];   // 28672 B
    __shared__ float s_t[512];                 // 2048 B
    __shared__ unsigned char s_v[512];         // 512 B   -> 31232 B total

    const int tid = threadIdx.x;
    const int rbase = blockIdx.x * 512;

    // -------- prologue: every global load, all before any store --------
    uint4 wst[7];
    {
        const uint4* src = reinterpret_cast<const uint4*>(wpack);
#pragma unroll
        for (int j = 0; j < 7; ++j)
            wst[j] = src[tid + j * 256];
    }
    const float t0 = times[rbase + tid];
    const float t1 = times[rbase + 256 + tid];
    const int v0i = vids[rbase + tid];
    const int v1i = vids[rbase + 256 + tid];

    {
        uint4* dst = reinterpret_cast<uint4*>(wl);
#pragma unroll
        for (int j = 0; j < 7; ++j)
            dst[tid + j * 256] = wst[j];
    }
    s_t[tid] = t0;
    s_t[tid + 256] = t1;
    s_v[tid] = (unsigned char)v0i;
    s_v[tid + 256] = (unsigned char)v1i;
    __syncthreads();

    const int q = tid & 7;
    const int g = tid >> 3;  // ray-group 0..31; slot = p*32+g, ray = rbase+slot

    uint4 wA[7], wB[7];
    {
        const int v = s_v[g];
        const unsigned b = (unsigned)v * 448u + (unsigned)(q ^ (v & 7)) * 8u;
#pragma unroll
        for (int i = 0; i < 7; ++i)
            wA[i] = *reinterpret_cast<const uint4*>(&wl[b + i * 64]);
    }

#define ITER(P, WCUR, WNEXT)                                                  \
    {                                                                         \
        if ((P) < 15) {  /* prefetch weights for slot P+1 */                  \
            const int nv = s_v[((P) + 1) * 32 + g];                           \
            const unsigned nb =                                               \
                (unsigned)nv * 448u + (unsigned)(q ^ (nv & 7)) * 8u;          \
            _Pragma("unroll")                                                 \
            for (int i = 0; i < 7; ++i)                                       \
                WNEXT[i] = *reinterpret_cast<const uint4*>(&wl[nb + i * 64]); \
        }                                                                     \
        const float t = s_t[(P) * 32 + g];                                    \
        h2 bp[7];                                                             \
        make_basis(t, bp);                                                    \
        float a0 = 0.f, a1 = 0.f, a2 = 0.f, a3 = 0.f;                         \
        _Pragma("unroll")                                                     \
        for (int i = 0; i < 7; ++i) {                                         \
            a0 = fdot2acc(__builtin_bit_cast(h2, WCUR[i].x), bp[i], a0);      \
            a1 = fdot2acc(__builtin_bit_cast(h2, WCUR[i].y), bp[i], a1);      \
            a2 = fdot2acc(__builtin_bit_cast(h2, WCUR[i].z), bp[i], a2);      \
            a3 = fdot2acc(__builtin_bit_cast(h2, WCUR[i].w), bp[i], a3);      \
        }                                                                     \
        f4 res;                                                               \
        res.x = a0; res.y = a1; res.z = a2; res.w = a3;                       \
        reinterpret_cast<f4*>(out)[(size_t)(rbase + (P) * 32 + g) * 8 + q] =  \
            res;                                                              \
    }

    for (int p = 0; p < 16; p += 2) {
        ITER(p, wA, wB)
        ITER(p + 1, wB, wA)
    }
#undef ITER
}

extern "C" void kernel_launch(void* const* d_in, const int* in_sizes, int n_in,
                              void* d_out, int out_size, void* d_ws, size_t ws_size,
                              hipStream_t stream) {
    const float* times = (const float*)d_in[0];
    const int* vids = (const int*)d_in[1];
    const float* weights = (const float*)d_in[2];
    float* out = (float*)d_out;
    unsigned* wpack = (unsigned*)d_ws;

    hipLaunchKernelGGL(pack_weights_kernel, dim3(28), dim3(256), 0, stream,
                       weights, wpack);
    // 2048 blocks x 512 contiguous rays; 5 blocks/CU (31232 B LDS).
    hipLaunchKernelGGL(VideoEmbedding_kernel, dim3(2048), dim3(256), 0, stream,
                       times, vids, wpack, out);
}